// Round 7
// baseline (108.713 us; speedup 1.0000x reference)
//
#include <hip/hip_runtime.h>
#include <hip/hip_bf16.h>
#include <stdint.h>

typedef __attribute__((ext_vector_type(8))) short short8;
typedef __attribute__((ext_vector_type(4))) float f32x4;
typedef __attribute__((ext_vector_type(4))) int i32x4;

#define RANGE  51200   // nodes per LDS half-range (u16 counters -> 100KB)
#define RWORDS 25600   // u32 words per range histogram
#define NSL    32      // edge slices; per-block edges = E/NSL <= 60000 (u16-safe)
#define NFRAG  16      // frag-prep blocks (16384 threads total)

static __device__ __forceinline__ short to_bf16s(float f) {
  __hip_bfloat16 h = __float2bfloat16(f);
  return __builtin_bit_cast(short, h);
}

// ---------------------------------------------------------------------------
// Fused: blocks [0,NFRAG) convert W1 -> bf16 MFMA B-fragments (+zero the
// grid-sync counter); blocks [NFRAG, NFRAG+2*NSL) build per-(slice,range)
// u16 histograms of src = edge_index[0] in LDS. dst is algebraically unused
// (the final mean over all nodes collapses segment_sum to sum_e h[src[e]]).
// u16 safety: each block sees <= E/NSL <= 60000 edges -> no overflow, no
// spill, no pre-zeroing of global, fire-and-forget LDS atomics.
__global__ __launch_bounds__(1024) void k_histprep(
    const int* __restrict__ e, unsigned* __restrict__ priv,
    short* __restrict__ frag, const float* __restrict__ W1,
    unsigned* __restrict__ ctr, int E) {
  __shared__ unsigned cnt[RWORDS];
  __shared__ int is64s;
  int b = blockIdx.x, tid = threadIdx.x;
  if (b < NFRAG) {
    if (b == 0 && tid == 0) *ctr = 0u;  // re-zero grid-sync counter each call
    int idx = b * 1024 + tid;  // k*128 + col
    int k = idx >> 7, col = idx & 127;
    int ct = col >> 4, ks = k >> 5, lh = (k >> 3) & 3, ee = k & 7;
    int lane = lh * 16 + (col & 15);
    frag[((ct * 4 + ks) * 64 + lane) * 8 + ee] = to_bf16s(W1[idx]);
    return;
  }
  int h = b - NFRAG;
  int r = h >> 5, s = h & (NSL - 1);  // range, edge-slice
  if (tid < 64) {  // layout detect: int64 -> high dwords all zero (LE)
    unsigned long long bl = __ballot(e[2 * tid + 1] == 0);
    if (tid == 0) is64s = (__popcll(bl) > 32) ? 1 : 0;
  }
  for (int j = tid; j < RWORDS; j += 1024) cnt[j] = 0u;
  __syncthreads();
  int is64 = is64s;
  unsigned base = (unsigned)r * RANGE;
  int nq = E >> 2;
  int qlo = (int)((long long)s * nq / NSL);
  int qhi = (int)((long long)(s + 1) * nq / NSL);
  for (int q = qlo + tid; q < qhi; q += 1024) {
    i32x4 v;
    if (is64) {
      i32x4 a = *reinterpret_cast<const i32x4*>(e + 8 * (size_t)q);
      i32x4 bb = *reinterpret_cast<const i32x4*>(e + 8 * (size_t)q + 4);
      v = i32x4{a[0], a[2], bb[0], bb[2]};
    } else {
      v = *reinterpret_cast<const i32x4*>(e + 4 * (size_t)q);
    }
#pragma unroll
    for (int k = 0; k < 4; ++k) {
      unsigned loc = (unsigned)v[k] - base;
      if (loc < (unsigned)RANGE)
        atomicAdd(&cnt[loc >> 1], 1u << (16 * (loc & 1)));
    }
  }
  if (s == 0) {  // tail edges (E%4), once per range
    int tail = E & 3;
    if (tid < tail) {
      int idx = E - tail + tid;
      unsigned loc = (unsigned)(is64 ? e[2 * idx] : e[idx]) - base;
      if (loc < (unsigned)RANGE)
        atomicAdd(&cnt[loc >> 1], 1u << (16 * (loc & 1)));
    }
  }
  __syncthreads();
  unsigned* dst = priv + (size_t)h * RWORDS;
  for (int j = tid; j < RWORDS; j += 1024) dst[j] = cnt[j];
}

// ---------------------------------------------------------------------------
// Fused main: s[j] = sum_n wdeg[n]*relu((X@W1)[n][j]+b1[j]); per-chunk wdeg
// reconstructed from priv in-kernel (merge kernel eliminated); partials
// reduced + epilogue MLP by the last-finishing block (red/final eliminated).
__global__ __launch_bounds__(256) void k_main(
    const float* __restrict__ X, const short* __restrict__ w1frag,
    const float* __restrict__ b1, const unsigned* __restrict__ priv,
    const float* __restrict__ wdegG, float* __restrict__ partials,
    unsigned* __restrict__ ctr, const float* __restrict__ W2,
    const float* __restrict__ b2, const float* __restrict__ Wp,
    const float* __restrict__ bp, float* __restrict__ out,
    float totalW, float invN, int nNodes) {
  __shared__ __align__(16) short w1s[16384];  // 32KB W1 B-frags
  __shared__ __align__(16) short xs[8192];    // 16KB A-tile (reused by finale)
  __shared__ __align__(16) float scratch[320]; // [0..255] degacc/sred, [256..319] wdeg_s
  __shared__ int lastFlag;

  int tid = threadIdx.x;
  {
    const f32x4* src = reinterpret_cast<const f32x4*>(w1frag);
    f32x4* dst = reinterpret_cast<f32x4*>(w1s);
#pragma unroll
    for (int i = 0; i < 8; ++i) dst[tid + i * 256] = src[tid + i * 256];
  }
  unsigned* degacc = (unsigned*)scratch;
  float* wdeg_s = scratch + 256;

  int lane = tid & 63, wave = tid >> 6;
  int rA = lane & 15;   // A-row in 16-row group / C-col low bits
  int kh = lane >> 4;   // k-offset group (0..3)

  float b1r[8];
#pragma unroll
  for (int ct = 0; ct < 8; ++ct) b1r[ct] = b1[ct * 16 + rA];

  float sl[8] = {0, 0, 0, 0, 0, 0, 0, 0};
  int nChunks = (nNodes + 63) >> 6;
  __syncthreads();

  for (int c = blockIdx.x; c < nChunks; c += gridDim.x) {
    int row0 = c << 6;
    // ---- stage X tile: 64 rows x 512B coalesced -> swizzled bf16 LDS ----
#pragma unroll
    for (int p = 0; p < 4; ++p) {
      int j = p * 256 + tid;  // 16B-unit id = row*16 + kc
      int rl = j >> 4, kc = j & 15;
      int grow = row0 + rl;
      if (grow > nNodes - 1) grow = nNodes - 1;
      const f32x4* gp =
          reinterpret_cast<const f32x4*>(X + (size_t)grow * 128 + kc * 8);
      f32x4 lo = gp[0], hi = gp[1];
      short8 v;
#pragma unroll
      for (int ee = 0; ee < 4; ++ee) {
        v[ee] = to_bf16s(lo[ee]);
        v[4 + ee] = to_bf16s(hi[ee]);
      }
      int u = rl * 16 + (kc ^ (rl & 7));
      *reinterpret_cast<short8*>(&xs[u * 8]) = v;
    }
    // ---- stage degree info for this chunk ----
    if (wdegG) {  // fallback: precomputed wdeg
      if (tid < 64) {
        int row = row0 + tid;
        wdeg_s[tid] = (row < nNodes) ? wdegG[row] : 0.f;
      }
    } else {      // fast: sum NSL u16 copies; chunk never straddles ranges
      int r = row0 / RANGE;
      int w0 = (row0 - r * RANGE) >> 1;
      int j = tid & 31, sg = tid >> 5;  // 32 words x 8 slice-groups
      const unsigned* pp =
          priv + ((size_t)(r * NSL + sg * 4)) * RWORDS + w0 + j;
      unsigned ssum = 0;
#pragma unroll
      for (int q = 0; q < 4; ++q) ssum += pp[(size_t)q * RWORDS];
      degacc[sg * 32 + j] = ssum;
    }
    __syncthreads();
    if (!wdegG && tid < 32) {  // fold 8 groups, unpack u16 pair
      unsigned wsum = 0;
#pragma unroll
      for (int g = 0; g < 8; ++g) wsum += degacc[g * 32 + tid];
      wdeg_s[2 * tid] = 1.0f + (float)(wsum & 0xFFFFu);
      wdeg_s[2 * tid + 1] = 1.0f + (float)(wsum >> 16);
    }
    // ---- MFMA: wave w owns local rows [w*16, w*16+16) ----
    int rloc = wave * 16 + rA;
    f32x4 acc[8];
#pragma unroll
    for (int ct = 0; ct < 8; ++ct) acc[ct] = f32x4{0.f, 0.f, 0.f, 0.f};
#pragma unroll
    for (int ks = 0; ks < 4; ++ks) {
      int kc = ks * 4 + kh;
      int u = rloc * 16 + (kc ^ (rloc & 7));
      short8 a = *reinterpret_cast<const short8*>(&xs[u * 8]);
#pragma unroll
      for (int ct = 0; ct < 8; ++ct) {
        short8 bfr = *reinterpret_cast<const short8*>(
            &w1s[((ct * 4 + ks) * 64 + lane) * 8]);
        acc[ct] = __builtin_amdgcn_mfma_f32_16x16x32_bf16(a, bfr, acc[ct], 0, 0, 0);
      }
    }
    __syncthreads();  // wdeg_s ready; xs reads drained
    // ---- epilogue: C elem (ct,rr): local row = wave*16+kh*4+rr ----
#pragma unroll
    for (int rr = 0; rr < 4; ++rr) {
      int rl = wave * 16 + kh * 4 + rr;
      float w = (row0 + rl < nNodes) ? wdeg_s[rl] : 0.0f;
#pragma unroll
      for (int ct = 0; ct < 8; ++ct)
        sl[ct] += w * fmaxf(acc[ct][rr] + b1r[ct], 0.f);
    }
    __syncthreads();  // protect xs/scratch before next chunk
  }

  // ---- block partial: fold lane groups -> scratch[0..127] -> partials ----
  if (tid < 128) scratch[tid] = 0.f;
  __syncthreads();
#pragma unroll
  for (int ct = 0; ct < 8; ++ct) {
    float v = sl[ct];
    v += __shfl_xor(v, 16);
    v += __shfl_xor(v, 32);
    if (kh == 0) atomicAdd(&scratch[ct * 16 + rA], v);
  }
  __syncthreads();
  if (tid < 128) partials[(size_t)blockIdx.x * 128 + tid] = scratch[tid];
  __threadfence();  // release: push partials past XCD L2
  if (tid == 0) {
    unsigned prev = atomicAdd(ctr, 1u);
    lastFlag = (prev == gridDim.x - 1);
  }
  __syncthreads();
  if (!lastFlag) return;
  __threadfence();  // acquire: discard any stale lines

  // ---- last block: reduce partials[B][128] + tiny MLP epilogue ----
  float* accsA = (float*)xs;       // 8*128
  float* sv = accsA + 1024;        // 128
  float* pooled = sv + 128;        // 128
  int B = (int)gridDim.x;
  {
    int cg = tid & 31, sl8 = tid >> 5;
    f32x4 s = f32x4{0.f, 0.f, 0.f, 0.f};
    for (int r = sl8; r < B; r += 8)
      s += *reinterpret_cast<const f32x4*>(partials + (size_t)r * 128 + cg * 4);
    *reinterpret_cast<f32x4*>(&accsA[sl8 * 128 + cg * 4]) = s;
  }
  __syncthreads();
  if (tid < 128) {
    float v = 0.f;
#pragma unroll
    for (int i = 0; i < 8; ++i) v += accsA[i * 128 + tid];
    sv[tid] = v;
  }
  __syncthreads();
  {  // pooled = (sv@W2 + totalW*b2)*invN ; 2 k-halves x 128 cols
    int col = tid & 127, half = tid >> 7;
    float a = 0.f;
#pragma unroll
    for (int kk = 0; kk < 64; ++kk) {
      int k = half * 64 + kk;
      a += sv[k] * W2[k * 128 + col];
    }
    accsA[half * 128 + col] = a;
  }
  __syncthreads();
  if (tid < 128)
    pooled[tid] = (accsA[tid] + accsA[128 + tid] + totalW * b2[tid]) * invN;
  __syncthreads();
  {  // out = pooled@Wp + bp ; 4 k-slices x 64 outs
    int o = tid & 63, s2 = tid >> 6;
    float a = 0.f;
#pragma unroll
    for (int kk = 0; kk < 32; ++kk) {
      int k = s2 * 32 + kk;
      a += pooled[k] * Wp[k * 64 + o];
    }
    accsA[s2 * 64 + o] = a;
  }
  __syncthreads();
  if (tid < 64)
    out[tid] = bp[tid] + accsA[tid] + accsA[64 + tid] + accsA[128 + tid] +
               accsA[192 + tid];
}

// ---------------------------------------------------------------------------
// Fallback path (ws too small / shapes out of range): zero + atomic hist + cvt.
__global__ void k_zero(unsigned* __restrict__ p, int n) {
  int i = blockIdx.x * 256 + threadIdx.x;
  if (i < n) p[i] = 0u;
}
__global__ __launch_bounds__(256) void k_hist_fb(const int* __restrict__ e,
                                                 unsigned* __restrict__ deg,
                                                 int E) {
  __shared__ int is64s;
  int tid = threadIdx.x;
  if (tid < 64) {
    unsigned long long bl = __ballot(e[2 * tid + 1] == 0);
    if (tid == 0) is64s = (__popcll(bl) > 32) ? 1 : 0;
  }
  __syncthreads();
  int is64 = is64s;
  int stride = gridDim.x * blockDim.x;
  for (int i = blockIdx.x * blockDim.x + tid; i < E; i += stride)
    atomicAdd(&deg[is64 ? (unsigned)e[2 * i] : (unsigned)e[i]], 1u);
}
__global__ void k_cvt(const unsigned* __restrict__ deg,
                      float* __restrict__ wdeg, int N) {
  int i = blockIdx.x * 256 + threadIdx.x;
  if (i < N) wdeg[i] = 1.0f + (float)deg[i];
}

// ---------------------------------------------------------------------------
extern "C" void kernel_launch(void* const* d_in, const int* in_sizes, int n_in,
                              void* d_out, int out_size, void* d_ws, size_t ws_size,
                              hipStream_t stream) {
  const float* X  = (const float*)d_in[0];
  const int*   ei = (const int*)d_in[1];
  const float* W1 = (const float*)d_in[2];
  const float* b1 = (const float*)d_in[3];
  const float* W2 = (const float*)d_in[4];
  const float* b2 = (const float*)d_in[5];
  const float* Wp = (const float*)d_in[6];
  const float* bp = (const float*)d_in[7];

  int N = in_sizes[0] / 128;
  int E = in_sizes[1] / 2;
  int nChunks = (N + 63) >> 6;
  int mb = nChunks < 782 ? nChunks : 782;  // <=2 chunks/block, ~3 blocks/CU

  size_t privB = (size_t)2 * NSL * RWORDS * 4;                // 6.55 MB
  size_t fragB = (16384 * 2 + 255) & ~(size_t)255;
  size_t wdegB = ((size_t)N * 4 + 255) & ~(size_t)255;        // fallback only
  size_t partB = ((size_t)mb * 128 * 4 + 255) & ~(size_t)255;
  size_t fixed = privB + fragB + wdegB + partB + 512;

  bool fast = (N <= 2 * RANGE - 64) && (E / NSL <= 60000) && (ws_size >= fixed);

  char* p = (char*)d_ws;
  unsigned* priv = (unsigned*)p;  p += privB;
  short* frag = (short*)p;        p += fragB;
  float* wdeg = (float*)p;        p += wdegB;
  float* parts = (float*)p;       p += partB;
  unsigned* ctr = (unsigned*)p;

  if (fast) {
    k_histprep<<<NFRAG + 2 * NSL, 1024, 0, stream>>>(ei, priv, frag, W1, ctr, E);
    k_main<<<mb, 256, 0, stream>>>(X, frag, b1, priv, (const float*)nullptr,
                                   parts, ctr, W2, b2, Wp, bp, (float*)d_out,
                                   (float)N + (float)E, 1.0f / (float)N, N);
  } else {
    k_histprep<<<NFRAG, 1024, 0, stream>>>(ei, priv, frag, W1, ctr, E);
    k_zero<<<(N + 255) / 256, 256, 0, stream>>>((unsigned*)wdeg, N);
    k_hist_fb<<<2048, 256, 0, stream>>>(ei, (unsigned*)wdeg, E);
    k_cvt<<<(N + 255) / 256, 256, 0, stream>>>((unsigned*)wdeg, wdeg, N);
    k_main<<<mb, 256, 0, stream>>>(X, frag, b1, priv, wdeg, parts, ctr, W2, b2,
                                   Wp, bp, (float*)d_out,
                                   (float)N + (float)E, 1.0f / (float)N, N);
  }
}

// Round 8
// 106.576 us; speedup vs baseline: 1.0201x; 1.0201x over previous
//
#include <hip/hip_runtime.h>
#include <hip/hip_bf16.h>
#include <stdint.h>

typedef __attribute__((ext_vector_type(8))) short short8;
typedef __attribute__((ext_vector_type(4))) float f32x4;
typedef __attribute__((ext_vector_type(4))) int i32x4;

#define RANGE  51200   // nodes per LDS half-range (u16 counters -> 100KB)
#define RWORDS 25600   // u32 words per range histogram
#define NSL    32      // edge slices; per-block edges = E/NSL <= 60000 (u16-safe)
#define NFRAG  16      // frag-prep blocks (16384 threads total)
#define NGRP   32      // level-1 reduction groups

static __device__ __forceinline__ short to_bf16s(float f) {
  __hip_bfloat16 h = __float2bfloat16(f);
  return __builtin_bit_cast(short, h);
}

// ---------------------------------------------------------------------------
// Fused: blocks [0,NFRAG) convert W1 -> bf16 MFMA B-fragments (+zero the
// arrival counters); blocks [NFRAG, NFRAG+2*NSL) build per-(slice,range)
// u16 histograms of src = edge_index[0] in LDS. dst is algebraically unused
// (the final mean over all nodes collapses segment_sum to sum_e h[src[e]]).
// u16 safety: each block sees <= E/NSL edges < 65535 -> no overflow, no
// spill, no global pre-zeroing, fire-and-forget LDS atomics.
__global__ __launch_bounds__(1024) void k_histprep(
    const int* __restrict__ e, unsigned* __restrict__ priv,
    short* __restrict__ frag, const float* __restrict__ W1,
    unsigned* __restrict__ ctrs, int E) {
  __shared__ unsigned cnt[RWORDS];
  __shared__ int is64s;
  int b = blockIdx.x, tid = threadIdx.x;
  if (b < NFRAG) {
    if (b == 0 && tid < NGRP + 1) ctrs[tid] = 0u;  // re-zero counters each call
    int idx = b * 1024 + tid;  // k*128 + col
    int k = idx >> 7, col = idx & 127;
    int ct = col >> 4, ks = k >> 5, lh = (k >> 3) & 3, ee = k & 7;
    int lane = lh * 16 + (col & 15);
    frag[((ct * 4 + ks) * 64 + lane) * 8 + ee] = to_bf16s(W1[idx]);
    return;
  }
  int h = b - NFRAG;
  int r = h >> 5, s = h & (NSL - 1);  // range, edge-slice
  if (tid < 64) {  // layout detect: int64 -> high dwords all zero (LE)
    unsigned long long bl = __ballot(e[2 * tid + 1] == 0);
    if (tid == 0) is64s = (__popcll(bl) > 32) ? 1 : 0;
  }
  for (int j = tid; j < RWORDS; j += 1024) cnt[j] = 0u;
  __syncthreads();
  int is64 = is64s;
  unsigned base = (unsigned)r * RANGE;
  int nq = E >> 2;
  int qlo = (int)((long long)s * nq / NSL);
  int qhi = (int)((long long)(s + 1) * nq / NSL);
  for (int q = qlo + tid; q < qhi; q += 1024) {
    i32x4 v;
    if (is64) {
      i32x4 a = *reinterpret_cast<const i32x4*>(e + 8 * (size_t)q);
      i32x4 bb = *reinterpret_cast<const i32x4*>(e + 8 * (size_t)q + 4);
      v = i32x4{a[0], a[2], bb[0], bb[2]};
    } else {
      v = *reinterpret_cast<const i32x4*>(e + 4 * (size_t)q);
    }
#pragma unroll
    for (int k = 0; k < 4; ++k) {
      unsigned loc = (unsigned)v[k] - base;
      if (loc < (unsigned)RANGE)
        atomicAdd(&cnt[loc >> 1], 1u << (16 * (loc & 1)));
    }
  }
  if (s == 0) {  // tail edges (E%4), once per range
    int tail = E & 3;
    if (tid < tail) {
      int idx = E - tail + tid;
      unsigned loc = (unsigned)(is64 ? e[2 * idx] : e[idx]) - base;
      if (loc < (unsigned)RANGE)
        atomicAdd(&cnt[loc >> 1], 1u << (16 * (loc & 1)));
    }
  }
  __syncthreads();
  unsigned* dst = priv + (size_t)h * RWORDS;
  for (int j = tid; j < RWORDS; j += 1024) dst[j] = cnt[j];
}

// ---------------------------------------------------------------------------
// Fused main: s[j] = sum_n wdeg[n]*relu((X@W1)[n][j]+b1[j]); per-chunk wdeg
// reconstructed from priv in-kernel; partials reduced via a deterministic
// two-level arrival tree (32 parallel group-reducers, then one finisher).
__global__ __launch_bounds__(256) void k_main(
    const float* __restrict__ X, const short* __restrict__ w1frag,
    const float* __restrict__ b1, const unsigned* __restrict__ priv,
    const float* __restrict__ wdegG, float* __restrict__ partials,
    float* __restrict__ gsum, unsigned* __restrict__ ctrs,
    const float* __restrict__ W2, const float* __restrict__ b2,
    const float* __restrict__ Wp, const float* __restrict__ bp,
    float* __restrict__ out, float totalW, float invN, int nNodes,
    int GS, int NG) {
  __shared__ __align__(16) short w1s[16384];  // 32KB W1 B-frags
  __shared__ __align__(16) short xs[8192];    // 16KB A-tile (reused as f32 scratch)
  __shared__ __align__(16) float scratch[320];
  __shared__ int lastF;

  int tid = threadIdx.x;
  {
    const f32x4* src = reinterpret_cast<const f32x4*>(w1frag);
    f32x4* dst = reinterpret_cast<f32x4*>(w1s);
#pragma unroll
    for (int i = 0; i < 8; ++i) dst[tid + i * 256] = src[tid + i * 256];
  }
  unsigned* degacc = (unsigned*)scratch;
  float* wdeg_s = scratch + 256;

  int lane = tid & 63, wave = tid >> 6;
  int rA = lane & 15;   // A-row in 16-row group / C-col low bits
  int kh = lane >> 4;   // k-offset group (0..3)

  float b1r[8];
#pragma unroll
  for (int ct = 0; ct < 8; ++ct) b1r[ct] = b1[ct * 16 + rA];

  float sl[8] = {0, 0, 0, 0, 0, 0, 0, 0};
  int nChunks = (nNodes + 63) >> 6;
  __syncthreads();

  for (int c = blockIdx.x; c < nChunks; c += gridDim.x) {
    int row0 = c << 6;
    // ---- stage X tile: 64 rows x 512B coalesced -> swizzled bf16 LDS ----
#pragma unroll
    for (int p = 0; p < 4; ++p) {
      int j = p * 256 + tid;  // 16B-unit id = row*16 + kc
      int rl = j >> 4, kc = j & 15;
      int grow = row0 + rl;
      if (grow > nNodes - 1) grow = nNodes - 1;
      const f32x4* gp =
          reinterpret_cast<const f32x4*>(X + (size_t)grow * 128 + kc * 8);
      f32x4 lo = gp[0], hi = gp[1];
      short8 v;
#pragma unroll
      for (int ee = 0; ee < 4; ++ee) {
        v[ee] = to_bf16s(lo[ee]);
        v[4 + ee] = to_bf16s(hi[ee]);
      }
      int u = rl * 16 + (kc ^ (rl & 7));
      *reinterpret_cast<short8*>(&xs[u * 8]) = v;
    }
    // ---- stage degree info for this chunk ----
    if (wdegG) {  // fallback: precomputed wdeg
      if (tid < 64) {
        int row = row0 + tid;
        wdeg_s[tid] = (row < nNodes) ? wdegG[row] : 0.f;
      }
    } else {      // fast: sum NSL u16 copies; chunk never straddles ranges
      int r = row0 / RANGE;
      int w0 = (row0 - r * RANGE) >> 1;
      int j = tid & 31, sg = tid >> 5;  // 32 words x 8 slice-groups
      const unsigned* pp =
          priv + ((size_t)(r * NSL + sg * 4)) * RWORDS + w0 + j;
      unsigned ssum = 0;
#pragma unroll
      for (int q = 0; q < 4; ++q) ssum += pp[(size_t)q * RWORDS];
      degacc[sg * 32 + j] = ssum;
    }
    __syncthreads();
    if (!wdegG && tid < 32) {  // fold 8 groups, unpack u16 pair
      unsigned wsum = 0;
#pragma unroll
      for (int g = 0; g < 8; ++g) wsum += degacc[g * 32 + tid];
      wdeg_s[2 * tid] = 1.0f + (float)(wsum & 0xFFFFu);
      wdeg_s[2 * tid + 1] = 1.0f + (float)(wsum >> 16);
    }
    // ---- MFMA: wave w owns local rows [w*16, w*16+16) ----
    int rloc = wave * 16 + rA;
    f32x4 acc[8];
#pragma unroll
    for (int ct = 0; ct < 8; ++ct) acc[ct] = f32x4{0.f, 0.f, 0.f, 0.f};
#pragma unroll
    for (int ks = 0; ks < 4; ++ks) {
      int kc = ks * 4 + kh;
      int u = rloc * 16 + (kc ^ (rloc & 7));
      short8 a = *reinterpret_cast<const short8*>(&xs[u * 8]);
#pragma unroll
      for (int ct = 0; ct < 8; ++ct) {
        short8 bfr = *reinterpret_cast<const short8*>(
            &w1s[((ct * 4 + ks) * 64 + lane) * 8]);
        acc[ct] = __builtin_amdgcn_mfma_f32_16x16x32_bf16(a, bfr, acc[ct], 0, 0, 0);
      }
    }
    __syncthreads();  // wdeg_s ready; xs reads drained
    // ---- epilogue: C elem (ct,rr): local row = wave*16+kh*4+rr ----
#pragma unroll
    for (int rr = 0; rr < 4; ++rr) {
      int rl = wave * 16 + kh * 4 + rr;
      float w = (row0 + rl < nNodes) ? wdeg_s[rl] : 0.0f;
#pragma unroll
      for (int ct = 0; ct < 8; ++ct)
        sl[ct] += w * fmaxf(acc[ct][rr] + b1r[ct], 0.f);
    }
    __syncthreads();  // protect xs/scratch before next chunk
  }

  // ---- block partial -> partials[blockIdx] ----
  if (tid < 128) scratch[tid] = 0.f;
  __syncthreads();
#pragma unroll
  for (int ct = 0; ct < 8; ++ct) {
    float v = sl[ct];
    v += __shfl_xor(v, 16);
    v += __shfl_xor(v, 32);
    if (kh == 0) atomicAdd(&scratch[ct * 16 + rA], v);
  }
  __syncthreads();
  if (tid < 128) partials[(size_t)blockIdx.x * 128 + tid] = scratch[tid];
  __threadfence();   // release (all threads)
  __syncthreads();   // order other threads' stores before tid0's atomic
  int g = blockIdx.x / GS;
  int r0 = g * GS;
  int cntg = min(GS, (int)gridDim.x - r0);
  if (tid == 0)
    lastF = (atomicAdd(&ctrs[1 + g], 1u) == (unsigned)(cntg - 1));
  __syncthreads();
  if (!lastF) return;
  __threadfence();   // acquire

  // ---- level-1: reduce this group's partials (fixed order) -> gsum[g] ----
  float* accsA = (float*)xs;   // 8*128 f32
  {
    int cg = tid & 31, sl8 = tid >> 5;
    f32x4 s = f32x4{0.f, 0.f, 0.f, 0.f};
    for (int r = sl8; r < cntg; r += 8)
      s += *reinterpret_cast<const f32x4*>(partials + (size_t)(r0 + r) * 128 + cg * 4);
    *reinterpret_cast<f32x4*>(&accsA[sl8 * 128 + cg * 4]) = s;
  }
  __syncthreads();
  if (tid < 128) {
    float v = 0.f;
#pragma unroll
    for (int i = 0; i < 8; ++i) v += accsA[i * 128 + tid];
    gsum[(size_t)g * 128 + tid] = v;
  }
  __threadfence();   // release
  __syncthreads();
  if (tid == 0)
    lastF = (atomicAdd(&ctrs[0], 1u) == (unsigned)(NG - 1));
  __syncthreads();
  if (!lastF) return;
  __threadfence();   // acquire

  // ---- level-2: reduce gsum[NG][128] + tiny MLP epilogue ----
  float* sv = accsA + 1024;
  float* pooled = sv + 128;
  {
    int cg = tid & 31, sl8 = tid >> 5;
    f32x4 s = f32x4{0.f, 0.f, 0.f, 0.f};
    for (int r = sl8; r < NG; r += 8)
      s += *reinterpret_cast<const f32x4*>(gsum + (size_t)r * 128 + cg * 4);
    *reinterpret_cast<f32x4*>(&accsA[sl8 * 128 + cg * 4]) = s;
  }
  __syncthreads();
  if (tid < 128) {
    float v = 0.f;
#pragma unroll
    for (int i = 0; i < 8; ++i) v += accsA[i * 128 + tid];
    sv[tid] = v;
  }
  __syncthreads();
  {  // pooled = (sv@W2 + totalW*b2)*invN ; 2 k-halves x 128 cols
    int col = tid & 127, half = tid >> 7;
    float a = 0.f;
#pragma unroll
    for (int kk = 0; kk < 64; ++kk) {
      int k = half * 64 + kk;
      a += sv[k] * W2[k * 128 + col];
    }
    accsA[half * 128 + col] = a;
  }
  __syncthreads();
  if (tid < 128)
    pooled[tid] = (accsA[tid] + accsA[128 + tid] + totalW * b2[tid]) * invN;
  __syncthreads();
  {  // out = pooled@Wp + bp ; 4 k-slices x 64 outs
    int o = tid & 63, s2 = tid >> 6;
    float a = 0.f;
#pragma unroll
    for (int kk = 0; kk < 32; ++kk) {
      int k = s2 * 32 + kk;
      a += pooled[k] * Wp[k * 64 + o];
    }
    accsA[s2 * 64 + o] = a;
  }
  __syncthreads();
  if (tid < 64)
    out[tid] = bp[tid] + accsA[tid] + accsA[64 + tid] + accsA[128 + tid] +
               accsA[192 + tid];
}

// ---------------------------------------------------------------------------
// Fallback path (ws too small / shapes out of range): zero + atomic hist + cvt.
__global__ void k_zero(unsigned* __restrict__ p, int n) {
  int i = blockIdx.x * 256 + threadIdx.x;
  if (i < n) p[i] = 0u;
}
__global__ __launch_bounds__(256) void k_hist_fb(const int* __restrict__ e,
                                                 unsigned* __restrict__ deg,
                                                 int E) {
  __shared__ int is64s;
  int tid = threadIdx.x;
  if (tid < 64) {
    unsigned long long bl = __ballot(e[2 * tid + 1] == 0);
    if (tid == 0) is64s = (__popcll(bl) > 32) ? 1 : 0;
  }
  __syncthreads();
  int is64 = is64s;
  int stride = gridDim.x * blockDim.x;
  for (int i = blockIdx.x * blockDim.x + tid; i < E; i += stride)
    atomicAdd(&deg[is64 ? (unsigned)e[2 * i] : (unsigned)e[i]], 1u);
}
__global__ void k_cvt(const unsigned* __restrict__ deg,
                      float* __restrict__ wdeg, int N) {
  int i = blockIdx.x * 256 + threadIdx.x;
  if (i < N) wdeg[i] = 1.0f + (float)deg[i];
}

// ---------------------------------------------------------------------------
extern "C" void kernel_launch(void* const* d_in, const int* in_sizes, int n_in,
                              void* d_out, int out_size, void* d_ws, size_t ws_size,
                              hipStream_t stream) {
  const float* X  = (const float*)d_in[0];
  const int*   ei = (const int*)d_in[1];
  const float* W1 = (const float*)d_in[2];
  const float* b1 = (const float*)d_in[3];
  const float* W2 = (const float*)d_in[4];
  const float* b2 = (const float*)d_in[5];
  const float* Wp = (const float*)d_in[6];
  const float* bp = (const float*)d_in[7];

  int N = in_sizes[0] / 128;
  int E = in_sizes[1] / 2;
  int nChunks = (N + 63) >> 6;
  int mb = nChunks < 782 ? nChunks : 782;  // <=2 chunks/block, ~3 blocks/CU
  int GS = (mb + NGRP - 1) / NGRP;         // level-1 group size
  int NG = (mb + GS - 1) / GS;             // number of groups

  size_t privB = (size_t)2 * NSL * RWORDS * 4;                // 6.55 MB
  size_t fragB = (16384 * 2 + 255) & ~(size_t)255;
  size_t wdegB = ((size_t)N * 4 + 255) & ~(size_t)255;        // fallback only
  size_t partB = ((size_t)mb * 128 * 4 + 255) & ~(size_t)255;
  size_t gsumB = ((size_t)NGRP * 128 * 4 + 255) & ~(size_t)255;
  size_t fixed = privB + fragB + wdegB + partB + gsumB + 512;

  bool fast = (N <= 2 * RANGE - 64) && (E / NSL <= 60000) && (ws_size >= fixed);

  char* p = (char*)d_ws;
  unsigned* priv = (unsigned*)p;  p += privB;
  short* frag = (short*)p;        p += fragB;
  float* wdeg = (float*)p;        p += wdegB;
  float* parts = (float*)p;       p += partB;
  float* gsum = (float*)p;        p += gsumB;
  unsigned* ctrs = (unsigned*)p;  // [0]=level2, [1..NGRP]=level1

  if (fast) {
    k_histprep<<<NFRAG + 2 * NSL, 1024, 0, stream>>>(ei, priv, frag, W1, ctrs, E);
    k_main<<<mb, 256, 0, stream>>>(X, frag, b1, priv, (const float*)nullptr,
                                   parts, gsum, ctrs, W2, b2, Wp, bp,
                                   (float*)d_out, (float)N + (float)E,
                                   1.0f / (float)N, N, GS, NG);
  } else {
    k_histprep<<<NFRAG, 1024, 0, stream>>>(ei, priv, frag, W1, ctrs, E);
    k_zero<<<(N + 255) / 256, 256, 0, stream>>>((unsigned*)wdeg, N);
    k_hist_fb<<<2048, 256, 0, stream>>>(ei, (unsigned*)wdeg, E);
    k_cvt<<<(N + 255) / 256, 256, 0, stream>>>((unsigned*)wdeg, wdeg, N);
    k_main<<<mb, 256, 0, stream>>>(X, frag, b1, priv, wdeg, parts, gsum, ctrs,
                                   W2, b2, Wp, bp, (float*)d_out,
                                   (float)N + (float)E, 1.0f / (float)N, N,
                                   GS, NG);
  }
}

// Round 9
// 39.147 us; speedup vs baseline: 2.7771x; 2.7225x over previous
//
#include <hip/hip_runtime.h>
#include <hip/hip_bf16.h>
#include <stdint.h>

typedef __attribute__((ext_vector_type(8))) short short8;
typedef __attribute__((ext_vector_type(4))) float f32x4;
typedef __attribute__((ext_vector_type(4))) int i32x4;

#define RANGE  51200   // nodes per LDS half-range (u16 counters -> 100KB); %64==0
#define RWORDS 25600   // u32 words per range histogram
#define NSL    32      // edge slices; per-block edges = E/NSL <= 60000 (u16-safe)
#define NFRAG  16      // frag-prep blocks (16384 threads total)

static __device__ __forceinline__ short to_bf16s(float f) {
  __hip_bfloat16 h = __float2bfloat16(f);
  return __builtin_bit_cast(short, h);
}

// ---------------------------------------------------------------------------
// Fused: blocks [0,NFRAG) convert W1 -> bf16 MFMA B-fragments; blocks
// [NFRAG, NFRAG+2*NSL) build per-(slice,range) u16 histograms of
// src = edge_index[0] in LDS. dst is algebraically unused (the final mean
// over all nodes collapses segment_sum to sum_e h[src[e]]).
// u16 safety: each block sees <= E/NSL edges < 65535 -> no overflow, no
// spill, no global pre-zeroing, fire-and-forget LDS atomics.
// NOTE: no __threadfence anywhere — agent-scope fences on gfx950 emit
// buffer_wbl2+buffer_inv (full L2 writeback+invalidate); 782 of them cost
// ~90us in R6/R7. Cross-kernel visibility via kernel-boundary semantics.
__global__ __launch_bounds__(1024) void k_histprep(
    const int* __restrict__ e, unsigned* __restrict__ priv,
    short* __restrict__ frag, const float* __restrict__ W1, int E) {
  __shared__ unsigned cnt[RWORDS];
  __shared__ int is64s;
  int b = blockIdx.x, tid = threadIdx.x;
  if (b < NFRAG) {
    int idx = b * 1024 + tid;  // k*128 + col
    int k = idx >> 7, col = idx & 127;
    int ct = col >> 4, ks = k >> 5, lh = (k >> 3) & 3, ee = k & 7;
    int lane = lh * 16 + (col & 15);
    frag[((ct * 4 + ks) * 64 + lane) * 8 + ee] = to_bf16s(W1[idx]);
    return;
  }
  int h = b - NFRAG;
  int r = h >> 5, s = h & (NSL - 1);  // range, edge-slice
  if (tid < 64) {  // layout detect: int64 -> high dwords all zero (LE)
    unsigned long long bl = __ballot(e[2 * tid + 1] == 0);
    if (tid == 0) is64s = (__popcll(bl) > 32) ? 1 : 0;
  }
  for (int j = tid; j < RWORDS; j += 1024) cnt[j] = 0u;
  __syncthreads();
  int is64 = is64s;
  unsigned base = (unsigned)r * RANGE;
  int nq = E >> 2;
  int qlo = (int)((long long)s * nq / NSL);
  int qhi = (int)((long long)(s + 1) * nq / NSL);
  for (int q = qlo + tid; q < qhi; q += 1024) {
    i32x4 v;
    if (is64) {
      i32x4 a = *reinterpret_cast<const i32x4*>(e + 8 * (size_t)q);
      i32x4 bb = *reinterpret_cast<const i32x4*>(e + 8 * (size_t)q + 4);
      v = i32x4{a[0], a[2], bb[0], bb[2]};
    } else {
      v = *reinterpret_cast<const i32x4*>(e + 4 * (size_t)q);
    }
#pragma unroll
    for (int k = 0; k < 4; ++k) {
      unsigned loc = (unsigned)v[k] - base;
      if (loc < (unsigned)RANGE)
        atomicAdd(&cnt[loc >> 1], 1u << (16 * (loc & 1)));
    }
  }
  if (s == 0) {  // tail edges (E%4), once per range
    int tail = E & 3;
    if (tid < tail) {
      int idx = E - tail + tid;
      unsigned loc = (unsigned)(is64 ? e[2 * idx] : e[idx]) - base;
      if (loc < (unsigned)RANGE)
        atomicAdd(&cnt[loc >> 1], 1u << (16 * (loc & 1)));
    }
  }
  __syncthreads();
  unsigned* dst = priv + (size_t)h * RWORDS;
  for (int j = tid; j < RWORDS; j += 1024) dst[j] = cnt[j];
}

// ---------------------------------------------------------------------------
// Main: s[j] = sum_n wdeg[n]*relu((X@W1)[n][j]+b1[j]); per-chunk wdeg
// reconstructed from priv in-kernel (merge fused); block partial -> plain
// store to partials[block][128]. No device-scope sync of any kind.
__global__ __launch_bounds__(256) void k_main(
    const float* __restrict__ X, const short* __restrict__ w1frag,
    const float* __restrict__ b1, const unsigned* __restrict__ priv,
    const float* __restrict__ wdegG, float* __restrict__ partials,
    int nNodes) {
  __shared__ __align__(16) short w1s[16384];  // 32KB W1 B-frags
  __shared__ __align__(16) short xs[8192];    // 16KB A-tile
  __shared__ __align__(16) float scratch[320];

  int tid = threadIdx.x;
  {
    const f32x4* src = reinterpret_cast<const f32x4*>(w1frag);
    f32x4* dst = reinterpret_cast<f32x4*>(w1s);
#pragma unroll
    for (int i = 0; i < 8; ++i) dst[tid + i * 256] = src[tid + i * 256];
  }
  unsigned* degacc = (unsigned*)scratch;
  float* wdeg_s = scratch + 256;

  int lane = tid & 63, wave = tid >> 6;
  int rA = lane & 15;   // A-row in 16-row group / C-col low bits
  int kh = lane >> 4;   // k-offset group (0..3)

  float b1r[8];
#pragma unroll
  for (int ct = 0; ct < 8; ++ct) b1r[ct] = b1[ct * 16 + rA];

  float sl[8] = {0, 0, 0, 0, 0, 0, 0, 0};
  int nChunks = (nNodes + 63) >> 6;
  __syncthreads();

  for (int c = blockIdx.x; c < nChunks; c += gridDim.x) {
    int row0 = c << 6;
    // ---- stage X tile: 64 rows x 512B coalesced -> swizzled bf16 LDS ----
#pragma unroll
    for (int p = 0; p < 4; ++p) {
      int j = p * 256 + tid;  // 16B-unit id = row*16 + kc
      int rl = j >> 4, kc = j & 15;
      int grow = row0 + rl;
      if (grow > nNodes - 1) grow = nNodes - 1;
      const f32x4* gp =
          reinterpret_cast<const f32x4*>(X + (size_t)grow * 128 + kc * 8);
      f32x4 lo = gp[0], hi = gp[1];
      short8 v;
#pragma unroll
      for (int ee = 0; ee < 4; ++ee) {
        v[ee] = to_bf16s(lo[ee]);
        v[4 + ee] = to_bf16s(hi[ee]);
      }
      int u = rl * 16 + (kc ^ (rl & 7));
      *reinterpret_cast<short8*>(&xs[u * 8]) = v;
    }
    // ---- stage degree info for this chunk ----
    if (wdegG) {  // fallback: precomputed wdeg
      if (tid < 64) {
        int row = row0 + tid;
        wdeg_s[tid] = (row < nNodes) ? wdegG[row] : 0.f;
      }
    } else {      // fast: sum NSL u16 copies; RANGE%64==0 -> no straddle
      int r = row0 / RANGE;
      int w0 = (row0 - r * RANGE) >> 1;
      int j = tid & 31, sg = tid >> 5;  // 32 words x 8 slice-groups
      const unsigned* pp =
          priv + ((size_t)(r * NSL + sg * 4)) * RWORDS + w0 + j;
      unsigned ssum = 0;
#pragma unroll
      for (int q = 0; q < 4; ++q) ssum += pp[(size_t)q * RWORDS];
      degacc[sg * 32 + j] = ssum;
    }
    __syncthreads();
    if (!wdegG && tid < 32) {  // fold 8 groups, unpack u16 pair
      unsigned wsum = 0;
#pragma unroll
      for (int g = 0; g < 8; ++g) wsum += degacc[g * 32 + tid];
      wdeg_s[2 * tid] = 1.0f + (float)(wsum & 0xFFFFu);
      wdeg_s[2 * tid + 1] = 1.0f + (float)(wsum >> 16);
    }
    // ---- MFMA: wave w owns local rows [w*16, w*16+16) ----
    int rloc = wave * 16 + rA;
    f32x4 acc[8];
#pragma unroll
    for (int ct = 0; ct < 8; ++ct) acc[ct] = f32x4{0.f, 0.f, 0.f, 0.f};
#pragma unroll
    for (int ks = 0; ks < 4; ++ks) {
      int kc = ks * 4 + kh;
      int u = rloc * 16 + (kc ^ (rloc & 7));
      short8 a = *reinterpret_cast<const short8*>(&xs[u * 8]);
#pragma unroll
      for (int ct = 0; ct < 8; ++ct) {
        short8 bfr = *reinterpret_cast<const short8*>(
            &w1s[((ct * 4 + ks) * 64 + lane) * 8]);
        acc[ct] = __builtin_amdgcn_mfma_f32_16x16x32_bf16(a, bfr, acc[ct], 0, 0, 0);
      }
    }
    __syncthreads();  // wdeg_s ready; xs reads drained
    // ---- epilogue: C elem (ct,rr): local row = wave*16+kh*4+rr ----
#pragma unroll
    for (int rr = 0; rr < 4; ++rr) {
      int rl = wave * 16 + kh * 4 + rr;
      float w = (row0 + rl < nNodes) ? wdeg_s[rl] : 0.0f;
#pragma unroll
      for (int ct = 0; ct < 8; ++ct)
        sl[ct] += w * fmaxf(acc[ct][rr] + b1r[ct], 0.f);
    }
    __syncthreads();  // protect xs/scratch before next chunk
  }

  // ---- block partial -> partials[blockIdx] (plain store) ----
  if (tid < 128) scratch[tid] = 0.f;
  __syncthreads();
#pragma unroll
  for (int ct = 0; ct < 8; ++ct) {
    float v = sl[ct];
    v += __shfl_xor(v, 16);
    v += __shfl_xor(v, 32);
    if (kh == 0) atomicAdd(&scratch[ct * 16 + rA], v);
  }
  __syncthreads();
  if (tid < 128) partials[(size_t)blockIdx.x * 128 + tid] = scratch[tid];
}

// ---------------------------------------------------------------------------
// Reduce partials[B][128] -> sv; out = ((sv@W2 + (N+E)*b2)/N)@Wp + bp.
// Single block, 1024 threads; 32-way sliced f32x4 reduction, unrolled MLP.
__global__ __launch_bounds__(1024) void k_final(
    const float* __restrict__ partials, int B, const float* __restrict__ W2,
    const float* __restrict__ b2, const float* __restrict__ Wp,
    const float* __restrict__ bp, float* __restrict__ out,
    float totalW, float invN) {
  __shared__ float accsA[32 * 128];  // 16KB
  __shared__ float sv[128];
  __shared__ float pooled[128];
  int t = threadIdx.x;
  {  // phase A: 32 slices x 32 f32x4 col-groups over B rows
    int cg = t & 31, slc = t >> 5;
    f32x4 s = f32x4{0.f, 0.f, 0.f, 0.f};
    for (int r = slc; r < B; r += 32)
      s += *reinterpret_cast<const f32x4*>(partials + (size_t)r * 128 + cg * 4);
    *reinterpret_cast<f32x4*>(&accsA[slc * 128 + cg * 4]) = s;
  }
  __syncthreads();
  if (t < 128) {
    float v = 0.f;
#pragma unroll
    for (int i = 0; i < 32; ++i) v += accsA[i * 128 + t];
    sv[t] = v;
  }
  __syncthreads();
  {  // pooled = (sv@W2 + totalW*b2)*invN ; 8 k-slices x 128 cols
    int col = t & 127, sl8 = t >> 7;
    float a = 0.f;
#pragma unroll
    for (int kk = 0; kk < 16; ++kk) {
      int k = sl8 * 16 + kk;
      a += sv[k] * W2[k * 128 + col];
    }
    accsA[sl8 * 128 + col] = a;
  }
  __syncthreads();
  if (t < 128) {
    float v = totalW * b2[t];
#pragma unroll
    for (int i = 0; i < 8; ++i) v += accsA[i * 128 + t];
    pooled[t] = v * invN;
  }
  __syncthreads();
  if (t < 512) {  // out = pooled@Wp + bp ; 64 outs x 8 k-slices
    int o = t & 63, s2 = t >> 6;
    float a = 0.f;
#pragma unroll
    for (int kk = 0; kk < 16; ++kk) {
      int k = s2 * 16 + kk;
      a += pooled[k] * Wp[k * 64 + o];
    }
    accsA[s2 * 64 + o] = a;
  }
  __syncthreads();
  if (t < 64) {
    float v = bp[t];
#pragma unroll
    for (int i = 0; i < 8; ++i) v += accsA[i * 64 + t];
    out[t] = v;
  }
}

// ---------------------------------------------------------------------------
// Fallback path (ws too small / shapes out of range): zero + atomic hist + cvt.
__global__ void k_zero(unsigned* __restrict__ p, int n) {
  int i = blockIdx.x * 256 + threadIdx.x;
  if (i < n) p[i] = 0u;
}
__global__ __launch_bounds__(256) void k_hist_fb(const int* __restrict__ e,
                                                 unsigned* __restrict__ deg,
                                                 int E) {
  __shared__ int is64s;
  int tid = threadIdx.x;
  if (tid < 64) {
    unsigned long long bl = __ballot(e[2 * tid + 1] == 0);
    if (tid == 0) is64s = (__popcll(bl) > 32) ? 1 : 0;
  }
  __syncthreads();
  int is64 = is64s;
  int stride = gridDim.x * blockDim.x;
  for (int i = blockIdx.x * blockDim.x + tid; i < E; i += stride)
    atomicAdd(&deg[is64 ? (unsigned)e[2 * i] : (unsigned)e[i]], 1u);
}
__global__ void k_cvt(const unsigned* __restrict__ deg,
                      float* __restrict__ wdeg, int N) {
  int i = blockIdx.x * 256 + threadIdx.x;
  if (i < N) wdeg[i] = 1.0f + (float)deg[i];
}

// ---------------------------------------------------------------------------
extern "C" void kernel_launch(void* const* d_in, const int* in_sizes, int n_in,
                              void* d_out, int out_size, void* d_ws, size_t ws_size,
                              hipStream_t stream) {
  const float* X  = (const float*)d_in[0];
  const int*   ei = (const int*)d_in[1];
  const float* W1 = (const float*)d_in[2];
  const float* b1 = (const float*)d_in[3];
  const float* W2 = (const float*)d_in[4];
  const float* b2 = (const float*)d_in[5];
  const float* Wp = (const float*)d_in[6];
  const float* bp = (const float*)d_in[7];

  int N = in_sizes[0] / 128;
  int E = in_sizes[1] / 2;
  int nChunks = (N + 63) >> 6;
  // grid sized for exact balance: 1563 chunks = 3 x 521 -> 3 chunks/block
  int mb = nChunks < 521 ? nChunks : 521;

  size_t privB = (size_t)2 * NSL * RWORDS * 4;                // 6.55 MB
  size_t fragB = (16384 * 2 + 255) & ~(size_t)255;
  size_t wdegB = ((size_t)N * 4 + 255) & ~(size_t)255;        // fallback only
  size_t partB = ((size_t)mb * 128 * 4 + 255) & ~(size_t)255;
  size_t fixed = privB + fragB + wdegB + partB + 512;

  bool fast = (N <= 2 * RANGE) && (E / NSL <= 60000) && (ws_size >= fixed);

  char* p = (char*)d_ws;
  unsigned* priv = (unsigned*)p;  p += privB;
  short* frag = (short*)p;        p += fragB;
  float* wdeg = (float*)p;        p += wdegB;
  float* parts = (float*)p;

  if (fast) {
    k_histprep<<<NFRAG + 2 * NSL, 1024, 0, stream>>>(ei, priv, frag, W1, E);
    k_main<<<mb, 256, 0, stream>>>(X, frag, b1, priv, (const float*)nullptr,
                                   parts, N);
  } else {
    k_histprep<<<NFRAG, 1024, 0, stream>>>(ei, priv, frag, W1, E);
    k_zero<<<(N + 255) / 256, 256, 0, stream>>>((unsigned*)wdeg, N);
    k_hist_fb<<<2048, 256, 0, stream>>>(ei, (unsigned*)wdeg, E);
    k_cvt<<<(N + 255) / 256, 256, 0, stream>>>((unsigned*)wdeg, wdeg, N);
    k_main<<<mb, 256, 0, stream>>>(X, frag, b1, priv, wdeg, parts, N);
  }
  k_final<<<1, 1024, 0, stream>>>(parts, mb, W2, b2, Wp, bp, (float*)d_out,
                                  (float)N + (float)E, 1.0f / (float)N);
}